// Round 7
// baseline (20003.821 us; speedup 1.0000x reference)
//
#include <hip/hip_runtime.h>
#include <cstdint>

#define HID 200
#define HALF 100
#define N_EDUS 32768
#define N_STEPS (2*N_EDUS - 1)   // 65535
#define KMAX 32766               // chain computes M_1..M_32766 (M_0 = enc[0])
#define PSTRIDE 500

typedef __fp16 h2v __attribute__((ext_vector_type(2)));
typedef _Float16 f16x8 __attribute__((ext_vector_type(8)));
typedef float f32x4 __attribute__((ext_vector_type(4)));

// ---------------- generic tiled GEMM: C[m][n] = bias[n] + sum_k A[m][k]*B[n][k] ----------------
// scat!=0: scatter-epilogue for P layout: n = g*100+rr -> col = (g<4) ? rr*4+g : 400+rr
__global__ __launch_bounds__(256) void gemm_bt(const float* __restrict__ A, int lda,
    const float* __restrict__ B, int ldb, const float* __restrict__ bias,
    float* __restrict__ C, int ldc, int M, int N, int K, int scat)
{
    __shared__ float As[32][68];
    __shared__ float Bs[32][68];
    const int tid = threadIdx.x;
    const int tx = tid & 15, ty = tid >> 4;
    const int m0 = blockIdx.x * 64, n0 = blockIdx.y * 64;
    float acc[4][4] = {};
    for (int kc = 0; kc < K; kc += 32) {
        const int kk = tid & 31, r0 = tid >> 5;
        #pragma unroll
        for (int p = 0; p < 8; ++p) {
            const int mm = r0 + p * 8;
            const int m = m0 + mm, n = n0 + mm, kg = kc + kk;
            As[kk][mm] = (m < M && kg < K) ? A[(size_t)m * lda + kg] : 0.f;
            Bs[kk][mm] = (n < N && kg < K) ? B[(size_t)n * ldb + kg] : 0.f;
        }
        __syncthreads();
        #pragma unroll
        for (int kk2 = 0; kk2 < 32; ++kk2) {
            const float4 a = *(const float4*)&As[kk2][tx * 4];
            const float4 b = *(const float4*)&Bs[kk2][ty * 4];
            const float av[4] = {a.x, a.y, a.z, a.w};
            const float bv[4] = {b.x, b.y, b.z, b.w};
            #pragma unroll
            for (int r = 0; r < 4; ++r)
                #pragma unroll
                for (int c = 0; c < 4; ++c)
                    acc[r][c] += av[r] * bv[c];
        }
        __syncthreads();
    }
    #pragma unroll
    for (int r = 0; r < 4; ++r) {
        const int m = m0 + tx * 4 + r;
        if (m >= M) continue;
        #pragma unroll
        for (int c = 0; c < 4; ++c) {
            const int n = n0 + ty * 4 + c;
            if (n < N) {
                const float v = acc[r][c] + (bias ? bias[n] : 0.f);
                int col = n;
                if (scat) {
                    const int q = n / 100, rr = n - q * 100;
                    col = (q < 4) ? rr * 4 + q : 400 + rr;
                }
                C[(size_t)m * ldc + col] = v;
            }
        }
    }
}

// ---------------- prep (loss weight stacking + missing projections) ----------------
// WAB columns are INTERLEAVED to match the interleaved M layout: col c <- inner (c>>1)+(c&1)*100
__global__ void prep_kernel(const float* __restrict__ W_act, const float* __restrict__ W_lab,
    const float* __restrict__ W_dir, const float* __restrict__ miss,
    float* __restrict__ WAB, float* __restrict__ WBC,
    float* __restrict__ msAB, float* __restrict__ msBC, float* __restrict__ out)
{
    const int tid = threadIdx.x;
    if (tid == 0) out[0] = 0.f;
    for (int i = tid; i < 48 * 200; i += 256) {
        const int r = i / 200, c = i % 200;
        const int rr = r % 24;
        const float* src = (rr < 2) ? (W_act + rr * 600)
                         : (rr < 21) ? (W_lab + (rr - 2) * 600)
                                     : (W_dir + (rr - 21) * 600);
        const int ci = (c >> 1) + (c & 1) * 100;   // interleaved inner index
        WAB[i] = src[ci + (r < 24 ? 0 : 200)];
        WBC[i] = src[c + (r < 24 ? 200 : 400)];
    }
    __syncthreads();
    if (tid < 48) {
        float sA = 0.f, sB = 0.f;
        for (int c = 0; c < 200; ++c) {
            sA += WAB[tid * 200 + c] * miss[(c >> 1) + (c & 1) * 100];
            sB += WBC[tid * 200 + c] * miss[c];
        }
        msAB[tid] = sA;
        msBC[tid] = sB;
    }
}

// ---------------- pack W_tree[:,0:100] into MFMA B-fragment layout (transpose form) ----
// D = h^T . W^T : B[k][n] with column n = gate-row. Wave w owns gate-rows [16w,16w+16) of
// all 5 gates. Frag id f = (w*5 + g)*4 + kc; lane l holds
// B[k = kc*32 + (l>>4)*8 + j][n = l&15] = W_tree[g*100 + w*16 + (l&15)][kc*32 + (l>>4)*8 + j],
// j=0..7 as f16 pairs (even k low half). Zero when gate-row >= 100 or k >= 100.
// (chain only consumes kc = 0..2; k = 96..99 goes through the WU path below)
__global__ __launch_bounds__(256) void pack_wb(const float* __restrict__ W_tree,
                                               uint4* __restrict__ WB)
{
    const int i = blockIdx.x * 256 + threadIdx.x;   // 140 frags * 64 lanes = 8960
    if (i >= 8960) return;
    const int lane = i & 63, f = i >> 6;
    const int kc = f & 3, gw = f >> 2;      // gw = w*5 + g
    const int g = gw % 5, w = gw / 5;
    const int row = w * 16 + (lane & 15);   // gate-row within gate g
    const int kb = kc * 32 + (lane >> 4) * 8;
    unsigned int dws[4];
    #pragma unroll
    for (int dw = 0; dw < 4; ++dw) {
        const int k0 = kb + dw * 2;
        float w0 = 0.f, w1 = 0.f;
        if (row < 100) {
            const float* Wr = W_tree + (size_t)(g * 100 + row) * 200;
            if (k0 < 100)     w0 = Wr[k0];
            if (k0 + 1 < 100) w1 = Wr[k0 + 1];
        }
        h2v h = __builtin_amdgcn_cvt_pkrtz(w0, w1);
        __builtin_memcpy(&dws[dw], &h, 4);
    }
    uint4 v; v.x = dws[0]; v.y = dws[1]; v.z = dws[2]; v.w = dws[3];
    WB[i] = v;
}

// ---------------- pack W_tree k=96..99 tail for the VALU dot2 path ----------------
// WU[(w*5+g)*64 + lane] = {pk(W[96],W[97]), pk(W[98],W[99])} for gate-row w*16+(lane&15).
// Replicated across kgrp (value depends only on lane&15). Zero when gate-row >= 100.
__global__ __launch_bounds__(256) void pack_wu(const float* __restrict__ W_tree,
                                               uint2* __restrict__ WU)
{
    const int i = blockIdx.x * 256 + threadIdx.x;   // 35 * 64 = 2240
    if (i >= 2240) return;
    const int lane = i & 63, gw = i >> 6;   // gw = w*5 + g
    const int g = gw % 5, w = gw / 5;
    const int row = w * 16 + (lane & 15);
    float a = 0.f, b = 0.f, c = 0.f, d = 0.f;
    if (row < 100) {
        const float* Wr = W_tree + (size_t)(g * 100 + row) * 200;
        a = Wr[96]; b = Wr[97]; c = Wr[98]; d = Wr[99];
    }
    h2v h01 = __builtin_amdgcn_cvt_pkrtz(a, b);
    h2v h23 = __builtin_amdgcn_cvt_pkrtz(c, d);
    uint2 v;
    __builtin_memcpy(&v.x, &h01, 4);
    __builtin_memcpy(&v.y, &h23, 4);
    WU[i] = v;
}

// ---------------- sequential treelstm chain (MFMA transpose form, 7 waves, 1 barrier) ----
__device__ __forceinline__ float sigf(float x) {
    return __builtin_amdgcn_rcpf(1.f + __expf(-x));
}
__device__ __forceinline__ float tanhf_(float x) {
    return 1.f - 2.f * __builtin_amdgcn_rcpf(1.f + __expf(2.f * x));
}
__device__ __forceinline__ h2v u2h(unsigned int u) { h2v h; __builtin_memcpy(&h, &u, 4); return h; }

// raw barrier: drain LDS only, leave global prefetch loads (vmcnt) in flight
#define BAR() asm volatile("s_waitcnt lgkmcnt(0)\n\ts_barrier" ::: "memory")

// One chain step. U = ring slot (0..3) & LDS parity (U&1), compile-time.
// A-operand = h broadcast (ds_read), B-operand = weights (registers). Lane l gets
// gate-row w*16+(l&15) directly in element 0 of each accumulator -> no gather.
// K split 96+4: MFMA covers k=0..95 (3 chunks), k=96..99 via 10 fdot2 off a broadcast
// ds_read_b64 (independent chain, hides under the MFMAs, folds into the gate add).
#define BODY(U, DOLOAD) \
{ \
    const uint4* hb = (const uint4*)(&hbuf[(U) & 1][0]); \
    f16x8 bb[3]; \
    { \
        uint4 t0 = hb[kgrp];      uint4 t1 = hb[4 + kgrp]; \
        uint4 t2 = hb[8 + kgrp]; \
        __builtin_memcpy(&bb[0], &t0, 16); __builtin_memcpy(&bb[1], &t1, 16); \
        __builtin_memcpy(&bb[2], &t2, 16); \
    } \
    const uint2 huu = *(const uint2*)(&hbuf[(U) & 1][96]); \
    const h2v h01 = u2h(huu.x), h23 = u2h(huu.y); \
    const float p0 = pr[U][0], p1 = pr[U][1], p2 = pr[U][2]; \
    const float p3 = pr[U][3], p4 = pr[U][4], c2v = pr[U][5]; \
    if (DOLOAD) { \
        const float4 g4 = *(const float4*)pP4; \
        pr[U][0] = g4.x; pr[U][1] = g4.y; pr[U][2] = g4.z; pr[U][3] = g4.w; \
        pr[U][4] = *pPu; \
        pP4 += PSTRIDE; pPu += PSTRIDE; \
        pr[U][5] = *pE; pE += HID; \
    } \
    float vp[5]; \
    _Pragma("unroll") \
    for (int g = 0; g < 5; ++g) \
        vp[g] = __builtin_amdgcn_fdot2(u2h(wu0[g]), h01, \
                 __builtin_amdgcn_fdot2(u2h(wu1[g]), h23, 0.f, false), false); \
    f32x4 acc[5]; \
    _Pragma("unroll") \
    for (int g = 0; g < 5; ++g) \
        acc[g] = __builtin_amdgcn_mfma_f32_16x16x32_f16(bb[0], Wf[g][0], z4, 0, 0, 0); \
    _Pragma("unroll") \
    for (int kc = 1; kc < 3; ++kc) \
        _Pragma("unroll") \
        for (int g = 0; g < 5; ++g) \
            acc[g] = __builtin_amdgcn_mfma_f32_16x16x32_f16(bb[kc], Wf[g][kc], acc[g], 0, 0, 0); \
    const float gi  = acc[0][0] + p0 + vp[0]; \
    const float gf1 = acc[1][0] + p1 + vp[1]; \
    const float gf2 = acc[2][0] + p2 + vp[2]; \
    const float go  = acc[3][0] + p3 + vp[3]; \
    const float gu  = acc[4][0] + p4 + vp[4]; \
    const float cnew = sigf(gi) * tanhf_(gu) + sigf(gf1) * c_sel + sigf(gf2) * c2v; \
    const float hnew = sigf(go) * tanhf_(cnew); \
    c_sel = cnew; \
    if (act) { \
        float2 hc; hc.x = hnew; hc.y = cnew; \
        *(float2*)pM = hc; \
        hbuf[((U) & 1) ^ 1][r] = (_Float16)hnew; \
    } \
    pM += HID; \
    BAR(); \
}

__attribute__((amdgpu_flat_work_group_size(448, 448), amdgpu_waves_per_eu(2, 2)))
__global__ void chain_kernel(const float* __restrict__ enc,
    const uint4* __restrict__ WB, const uint2* __restrict__ WU,
    const float* __restrict__ P, float* __restrict__ M)
{
    const int T = threadIdx.x;
    const int wave = T >> 6, lane = T & 63;
    const int col = lane & 15, kgrp = lane >> 4;
    const int r = wave * 16 + col;          // gate-row this lane owns (0..111)
    const int rc = (r < 100) ? r : 99;      // clamped for loads
    const bool act = (kgrp == 0) && (r < 100);
    __shared__ __align__(16) _Float16 hbuf[2][128];

    // M_0 = enc[0], interleaved (h0,c0,h1,c1,...)
    if (T < 100) {
        float2 hc; hc.x = enc[T]; hc.y = enc[100 + T];
        *(float2*)(M + 2 * T) = hc;
    }
    if (T < 128) {
        hbuf[0][T] = (T < 100) ? (_Float16)enc[T] : (_Float16)0.f;  // h of M_0, zero pad
        hbuf[1][T] = (_Float16)0.f;                                  // pad rows stay 0 forever
    }

    // W B-fragments in registers/AGPRs for the whole chain: 15 frags x 16B per wave
    f16x8 Wf[5][3];
    #pragma unroll
    for (int g = 0; g < 5; ++g)
        #pragma unroll
        for (int kc = 0; kc < 3; ++kc) {
            uint4 tt = WB[(((wave * 5 + g) * 4) + kc) * 64 + lane];
            __builtin_memcpy(&Wf[g][kc], &tt, 16);
        }
    // k=96..99 tail weights: 10 dwords (f16 pairs) per lane
    unsigned int wu0[5], wu1[5];
    #pragma unroll
    for (int g = 0; g < 5; ++g) {
        uint2 t = WU[(wave * 5 + g) * 64 + lane];
        wu0[g] = t.x; wu1[g] = t.y;
    }
    f32x4 z4 = {0.f, 0.f, 0.f, 0.f};   // hoisted zero C-operand (no per-step acc init)

    float c_sel = enc[100 + rc];        // c of M_0 for this lane's row

    // 4-deep prefetch ring: slot u holds P row (1+u) gate biases + enc c2 row (1+u)
    float pr[4][6];
    #pragma unroll
    for (int u = 0; u < 4; ++u) {
        const float* pu4 = P + (size_t)(1 + u) * PSTRIDE + rc * 4;   // 16B aligned
        const float4 g4 = *(const float4*)pu4;
        pr[u][0] = g4.x; pr[u][1] = g4.y; pr[u][2] = g4.z; pr[u][3] = g4.w;
        pr[u][4] = P[(size_t)(1 + u) * PSTRIDE + 400 + rc];
        pr[u][5] = enc[(size_t)(1 + u) * HID + 100 + rc];
    }
    const float* pP4 = P + (size_t)5 * PSTRIDE + rc * 4;   // next prefetch = step 5
    const float* pPu = P + (size_t)5 * PSTRIDE + 400 + rc;
    const float* pE  = enc + (size_t)5 * HID + 100 + rc;
    float* pM = M + HID + 2 * r;                           // step-1 store slot (act-guarded)
    BAR();

    // main loop: 8190 iterations x 4 steps = steps 1..32760
    for (int base = 1; base <= KMAX - 9; base += 4) {
        BODY(0, true);
        BODY(1, true);
        BODY(2, true);
        BODY(3, true);
    }
    // tail: steps 32761..32766 (slots 0,1 reloaded for 32765/32766)
    BODY(0, true);
    BODY(1, true);
    BODY(2, false);
    BODY(3, false);
    BODY(0, false);
    BODY(1, false);
}

// ---------------- per-step CE losses + reduction ----------------
__global__ __launch_bounds__(256) void loss_kernel(const float* __restrict__ TM,
    const float* __restrict__ TE, const float* __restrict__ msAB, const float* __restrict__ msBC,
    const float* __restrict__ b_act, const float* __restrict__ b_lab, const float* __restrict__ b_dir,
    const int* __restrict__ ga, const int* __restrict__ gl, const int* __restrict__ gd,
    float* __restrict__ out)
{
    const int t = blockIdx.x * 256 + threadIdx.x;
    float loss = 0.f;
    if (t < N_STEPS) {
        const float *v1, *v0, *vb;
        if (t == 0)      { v1 = msAB; v0 = msAB + 24; vb = TE + 24; }
        else if (t == 1) { v1 = msAB; v0 = TE;        vb = TE + 48 + 24; }
        else if ((t & 1) == 0) {
            const int k = t >> 1;
            v1 = TM + (size_t)(k - 1) * 48;
            v0 = TE + (size_t)k * 48;
            vb = (k < N_EDUS - 1) ? (TE + (size_t)(k + 1) * 48 + 24) : (msBC + 24);
        } else {
            const int k = t >> 1;
            v1 = msAB;
            v0 = TM + (size_t)k * 48 + 24;
            vb = TE + (size_t)(k + 1) * 48 + 24;
        }
        float l[24];
        #pragma unroll
        for (int j = 0; j < 24; ++j) l[j] = v1[j] + v0[j] + vb[j];
        l[0] += b_act[0]; l[1] += b_act[1];
        #pragma unroll
        for (int j = 0; j < 19; ++j) l[2 + j] += b_lab[j];
        #pragma unroll
        for (int j = 0; j < 3; ++j) l[21 + j] += b_dir[j];
        const int ya = ga[t], yl = gl[t], yd = gd[t];
        {
            const float m = fmaxf(l[0], l[1]);
            const float sum = __expf(l[0] - m) + __expf(l[1] - m);
            loss += m + __logf(sum) - (ya == 0 ? l[0] : l[1]);
        }
        {
            float m = l[2];
            #pragma unroll
            for (int j = 1; j < 19; ++j) m = fmaxf(m, l[2 + j]);
            float sum = 0.f, ly = 0.f;
            #pragma unroll
            for (int j = 0; j < 19; ++j) {
                sum += __expf(l[2 + j] - m);
                if (j == yl) ly = l[2 + j];
            }
            loss += m + __logf(sum) - ly;
        }
        {
            const float m = fmaxf(fmaxf(l[21], l[22]), l[23]);
            const float sum = __expf(l[21] - m) + __expf(l[22] - m) + __expf(l[23] - m);
            const float ly = (yd == 0) ? l[21] : (yd == 1 ? l[22] : l[23]);
            loss += m + __logf(sum) - ly;
        }
    }
    #pragma unroll
    for (int off = 32; off > 0; off >>= 1) loss += __shfl_down(loss, off, 64);
    __shared__ float wsum[4];
    const int lane = threadIdx.x & 63, wv = threadIdx.x >> 6;
    if (lane == 0) wsum[wv] = loss;
    __syncthreads();
    if (threadIdx.x == 0) atomicAdd(out, wsum[0] + wsum[1] + wsum[2] + wsum[3]);
}

// ---------------- launch ----------------
extern "C" void kernel_launch(void* const* d_in, const int* in_sizes, int n_in,
                              void* d_out, int out_size, void* d_ws, size_t ws_size,
                              hipStream_t stream) {
    const float* enc_cls = (const float*)d_in[0];
    const float* W_proj  = (const float*)d_in[1];
    const float* b_proj  = (const float*)d_in[2];
    const float* miss    = (const float*)d_in[3];
    const float* W_act   = (const float*)d_in[4];
    const float* b_act   = (const float*)d_in[5];
    const float* W_lab   = (const float*)d_in[6];
    const float* b_lab   = (const float*)d_in[7];
    const float* W_dir   = (const float*)d_in[8];
    const float* b_dir   = (const float*)d_in[9];
    const float* W_tree  = (const float*)d_in[10];
    const float* b_tree  = (const float*)d_in[11];
    const int*   ga      = (const int*)d_in[12];
    const int*   gl      = (const int*)d_in[13];
    const int*   gd      = (const int*)d_in[14];
    float* out = (float*)d_out;

    float* ws   = (float*)d_ws;
    float* enc  = ws;                         // 32768*200
    float* Mar  = ws + 6553600;               // 32767*200 (interleaved h,c pairs)
    float* P    = ws + 13107000;              // 32767*500 (4+1 gate layout, row 0 unused)
    float* WAB  = ws + 29490500;              // 48*200 (interleaved cols)
    float* WBC  = WAB + 9600;                 // 48*200
    float* msAB = WBC + 9600;                 // 48
    float* msBC = msAB + 48;                  // 48
    uint4* WB   = (uint4*)(msBC + 48);        // 8960 uint4 = 35840 dwords (B-frags)
    uint2* WU   = (uint2*)(WB + 8960);        // 2240 uint2 (k=96..99 tail weights)
    float* TM = P;                            // 32767*48 (overlays dead P)
    float* TE = P + 1572816;                  // 32768*48

    gemm_bt<<<dim3(512, 4, 1), 256, 0, stream>>>(enc_cls, 768, W_proj, 768, b_proj,
                                                 enc, 200, N_EDUS, 200, 768, 0);
    gemm_bt<<<dim3(512, 8, 1), 256, 0, stream>>>(enc + 200, 200, W_tree + 100, 200, b_tree,
                                                 P + PSTRIDE, PSTRIDE, KMAX, 500, 100, 1);
    prep_kernel<<<1, 256, 0, stream>>>(W_act, W_lab, W_dir, miss, WAB, WBC, msAB, msBC, out);
    pack_wb<<<35, 256, 0, stream>>>(W_tree, WB);
    pack_wu<<<9, 256, 0, stream>>>(W_tree, WU);
    chain_kernel<<<1, 448, 0, stream>>>(enc, WB, WU, P, Mar);
    gemm_bt<<<dim3(512, 1, 1), 256, 0, stream>>>(Mar, 200, WAB, 200, nullptr,
                                                 TM, 48, KMAX + 1, 48, 200, 0);
    gemm_bt<<<dim3(512, 1, 1), 256, 0, stream>>>(enc, 200, WBC, 200, nullptr,
                                                 TE, 48, N_EDUS, 48, 200, 0);
    loss_kernel<<<dim3(256, 1, 1), 256, 0, stream>>>(TM, TE, msAB, msBC,
                                                     b_act, b_lab, b_dir, ga, gl, gd, out);
}

// Round 8
// 17012.286 us; speedup vs baseline: 1.1758x; 1.1758x over previous
//
#include <hip/hip_runtime.h>
#include <cstdint>

#define HID 200
#define HALF 100
#define N_EDUS 32768
#define N_STEPS (2*N_EDUS - 1)   // 65535
#define KMAX 32766               // chain computes M_1..M_32766 (M_0 = enc[0])
#define PSTRIDE 500
#define L2E   1.4426950408889634f
#define L2E2  2.8853900817779268f

typedef __fp16 h2v __attribute__((ext_vector_type(2)));
typedef _Float16 f16x8 __attribute__((ext_vector_type(8)));
typedef float f32x4 __attribute__((ext_vector_type(4)));

// ---------------- generic tiled GEMM: C[m][n] = bias[n] + sum_k A[m][k]*B[n][k] ----------------
// scat!=0: scatter-epilogue for P layout: n = g*100+rr -> col = (g<4) ? rr*4+g : 400+rr,
// value scaled by log2e (sigmoid gates) / 2*log2e (u gate) for the exp2-direct combine.
__global__ __launch_bounds__(256) void gemm_bt(const float* __restrict__ A, int lda,
    const float* __restrict__ B, int ldb, const float* __restrict__ bias,
    float* __restrict__ C, int ldc, int M, int N, int K, int scat)
{
    __shared__ float As[32][68];
    __shared__ float Bs[32][68];
    const int tid = threadIdx.x;
    const int tx = tid & 15, ty = tid >> 4;
    const int m0 = blockIdx.x * 64, n0 = blockIdx.y * 64;
    float acc[4][4] = {};
    for (int kc = 0; kc < K; kc += 32) {
        const int kk = tid & 31, r0 = tid >> 5;
        #pragma unroll
        for (int p = 0; p < 8; ++p) {
            const int mm = r0 + p * 8;
            const int m = m0 + mm, n = n0 + mm, kg = kc + kk;
            As[kk][mm] = (m < M && kg < K) ? A[(size_t)m * lda + kg] : 0.f;
            Bs[kk][mm] = (n < N && kg < K) ? B[(size_t)n * ldb + kg] : 0.f;
        }
        __syncthreads();
        #pragma unroll
        for (int kk2 = 0; kk2 < 32; ++kk2) {
            const float4 a = *(const float4*)&As[kk2][tx * 4];
            const float4 b = *(const float4*)&Bs[kk2][ty * 4];
            const float av[4] = {a.x, a.y, a.z, a.w};
            const float bv[4] = {b.x, b.y, b.z, b.w};
            #pragma unroll
            for (int r = 0; r < 4; ++r)
                #pragma unroll
                for (int c = 0; c < 4; ++c)
                    acc[r][c] += av[r] * bv[c];
        }
        __syncthreads();
    }
    #pragma unroll
    for (int r = 0; r < 4; ++r) {
        const int m = m0 + tx * 4 + r;
        if (m >= M) continue;
        #pragma unroll
        for (int c = 0; c < 4; ++c) {
            const int n = n0 + ty * 4 + c;
            if (n < N) {
                float v = acc[r][c] + (bias ? bias[n] : 0.f);
                int col = n;
                if (scat) {
                    const int q = n / 100, rr = n - q * 100;
                    col = (q < 4) ? rr * 4 + q : 400 + rr;
                    v *= (q == 4) ? L2E2 : L2E;
                }
                C[(size_t)m * ldc + col] = v;
            }
        }
    }
}

// ---------------- prep (loss weight stacking + missing projections) ----------------
// WAB columns are INTERLEAVED to match the interleaved M layout: col c <- inner (c>>1)+(c&1)*100
__global__ void prep_kernel(const float* __restrict__ W_act, const float* __restrict__ W_lab,
    const float* __restrict__ W_dir, const float* __restrict__ miss,
    float* __restrict__ WAB, float* __restrict__ WBC,
    float* __restrict__ msAB, float* __restrict__ msBC, float* __restrict__ out)
{
    const int tid = threadIdx.x;
    if (tid == 0) out[0] = 0.f;
    for (int i = tid; i < 48 * 200; i += 256) {
        const int r = i / 200, c = i % 200;
        const int rr = r % 24;
        const float* src = (rr < 2) ? (W_act + rr * 600)
                         : (rr < 21) ? (W_lab + (rr - 2) * 600)
                                     : (W_dir + (rr - 21) * 600);
        const int ci = (c >> 1) + (c & 1) * 100;   // interleaved inner index
        WAB[i] = src[ci + (r < 24 ? 0 : 200)];
        WBC[i] = src[c + (r < 24 ? 200 : 400)];
    }
    __syncthreads();
    if (tid < 48) {
        float sA = 0.f, sB = 0.f;
        for (int c = 0; c < 200; ++c) {
            sA += WAB[tid * 200 + c] * miss[(c >> 1) + (c & 1) * 100];
            sB += WBC[tid * 200 + c] * miss[c];
        }
        msAB[tid] = sA;
        msBC[tid] = sB;
    }
}

// ---------------- pack W_tree[:,0:100] into MFMA B-fragment layout (transpose form) ----
// D = h^T . W^T : B[k][n] with column n = gate-row. Wave w owns gate-rows [16w,16w+16) of
// all 5 gates. Frag id f = (w*5 + g)*4 + kc; lane l holds
// B[k = kc*32 + (l>>4)*8 + j][n = l&15] = W_tree[g*100 + w*16 + (l&15)][kc*32 + (l>>4)*8 + j],
// j=0..7 as f16 pairs (even k low half). Zero when gate-row >= 100 or k >= 100.
// Weights pre-scaled by log2e (2*log2e for u gate) for the exp2-direct combine.
__global__ __launch_bounds__(256) void pack_wb(const float* __restrict__ W_tree,
                                               uint4* __restrict__ WB)
{
    const int i = blockIdx.x * 256 + threadIdx.x;   // 140 frags * 64 lanes = 8960
    if (i >= 8960) return;
    const int lane = i & 63, f = i >> 6;
    const int kc = f & 3, gw = f >> 2;      // gw = w*5 + g
    const int g = gw % 5, w = gw / 5;
    const int row = w * 16 + (lane & 15);   // gate-row within gate g
    const int kb = kc * 32 + (lane >> 4) * 8;
    const float sc = (g == 4) ? L2E2 : L2E;
    unsigned int dws[4];
    #pragma unroll
    for (int dw = 0; dw < 4; ++dw) {
        const int k0 = kb + dw * 2;
        float w0 = 0.f, w1 = 0.f;
        if (row < 100) {
            const float* Wr = W_tree + (size_t)(g * 100 + row) * 200;
            if (k0 < 100)     w0 = Wr[k0] * sc;
            if (k0 + 1 < 100) w1 = Wr[k0 + 1] * sc;
        }
        h2v h = __builtin_amdgcn_cvt_pkrtz(w0, w1);
        __builtin_memcpy(&dws[dw], &h, 4);
    }
    uint4 v; v.x = dws[0]; v.y = dws[1]; v.z = dws[2]; v.w = dws[3];
    WB[i] = v;
}

// ---------------- sequential treelstm chain (MFMA transpose form, 7 waves, 1 barrier) ----
// raw barrier: drain LDS only, leave global prefetch loads (vmcnt) in flight
#define BAR() asm volatile("s_waitcnt lgkmcnt(0)\n\ts_barrier" ::: "memory")

// One chain step. U = ring slot (0..3) & LDS parity (U&1), compile-time.
// A-operand = h broadcast (ds_read), B-operand = weights (registers). Lane l gets
// gate-row w*16+(l&15) directly in element 0 of each accumulator -> no gather.
// Gate bias folded into MFMA C element 0 (acc is step-persistent; stale elements 1-3
// are finite don't-cares). Combine uses pre-scaled exp2-direct sigmoid/tanh:
//   sig(x) = rcp(1+2^(-y)), y = x*log2e (pre-scaled);  tanh(x) = 1-2*rcp(1+2^y), y = 2x*log2e.
#define BODY(U, DOLOAD) \
{ \
    const uint4* hb = (const uint4*)(&hbuf[(U) & 1][0]); \
    f16x8 bb[4]; \
    { \
        uint4 t0 = hb[kgrp];      uint4 t1 = hb[4 + kgrp]; \
        uint4 t2 = hb[8 + kgrp];  uint4 t3 = hb[12 + kgrp]; \
        __builtin_memcpy(&bb[0], &t0, 16); __builtin_memcpy(&bb[1], &t1, 16); \
        __builtin_memcpy(&bb[2], &t2, 16); __builtin_memcpy(&bb[3], &t3, 16); \
    } \
    const float p0 = pr[U][0], p1 = pr[U][1], p2 = pr[U][2]; \
    const float p3 = pr[U][3], p4 = pr[U][4], c2v = pr[U][5]; \
    if (DOLOAD) { \
        const float4 g4 = *(const float4*)pP4; \
        pr[U][0] = g4.x; pr[U][1] = g4.y; pr[U][2] = g4.z; pr[U][3] = g4.w; \
        pr[U][4] = *pPu; \
        pP4 += PSTRIDE; pPu += PSTRIDE; \
        pr[U][5] = *pE; pE += HID; \
    } \
    acc[0][0] = p0; acc[1][0] = p1; acc[2][0] = p2; acc[3][0] = p3; acc[4][0] = p4; \
    _Pragma("unroll") \
    for (int kc = 0; kc < 4; ++kc) \
        _Pragma("unroll") \
        for (int g = 0; g < 5; ++g) \
            acc[g] = __builtin_amdgcn_mfma_f32_16x16x32_f16(bb[kc], Wf[g][kc], acc[g], 0, 0, 0); \
    const float gi  = acc[0][0]; \
    const float gf1 = acc[1][0]; \
    const float gf2 = acc[2][0]; \
    const float go  = acc[3][0]; \
    const float gu  = acc[4][0]; \
    const float si  = __builtin_amdgcn_rcpf(1.f + __builtin_amdgcn_exp2f(-gi)); \
    const float sf1 = __builtin_amdgcn_rcpf(1.f + __builtin_amdgcn_exp2f(-gf1)); \
    const float sf2 = __builtin_amdgcn_rcpf(1.f + __builtin_amdgcn_exp2f(-gf2)); \
    const float so  = __builtin_amdgcn_rcpf(1.f + __builtin_amdgcn_exp2f(-go)); \
    const float tu  = 1.f - 2.f * __builtin_amdgcn_rcpf(1.f + __builtin_amdgcn_exp2f(gu)); \
    const float cnew = si * tu + sf1 * c_sel + sf2 * c2v; \
    const float tc  = 1.f - 2.f * __builtin_amdgcn_rcpf(1.f + __builtin_amdgcn_exp2f(cnew * L2E2)); \
    const float hnew = so * tc; \
    c_sel = cnew; \
    if (act) { \
        hbuf[((U) & 1) ^ 1][r] = (_Float16)hnew; \
        float2 hc; hc.x = hnew; hc.y = cnew; \
        *(float2*)pM = hc; \
    } \
    pM += HID; \
    BAR(); \
}

__attribute__((amdgpu_flat_work_group_size(448, 448), amdgpu_waves_per_eu(2, 2)))
__global__ void chain_kernel(const float* __restrict__ enc,
    const uint4* __restrict__ WB, const float* __restrict__ P, float* __restrict__ M)
{
    const int T = threadIdx.x;
    const int wave = T >> 6, lane = T & 63;
    const int col = lane & 15, kgrp = lane >> 4;
    const int r = wave * 16 + col;          // gate-row this lane owns (0..111)
    const int rc = (r < 100) ? r : 99;      // clamped for loads
    const bool act = (kgrp == 0) && (r < 100);
    __shared__ __align__(16) _Float16 hbuf[2][128];

    // M_0 = enc[0], interleaved (h0,c0,h1,c1,...)
    if (T < 100) {
        float2 hc; hc.x = enc[T]; hc.y = enc[100 + T];
        *(float2*)(M + 2 * T) = hc;
    }
    if (T < 128) {
        hbuf[0][T] = (T < 100) ? (_Float16)enc[T] : (_Float16)0.f;  // h of M_0, zero pad
        hbuf[1][T] = (_Float16)0.f;                                  // pad rows stay 0 forever
    }

    // W B-fragments in registers/AGPRs for the whole chain: 20 frags x 16B per wave
    f16x8 Wf[5][4];
    #pragma unroll
    for (int g = 0; g < 5; ++g)
        #pragma unroll
        for (int kc = 0; kc < 4; ++kc) {
            uint4 tt = WB[(((wave * 5 + g) * 4) + kc) * 64 + lane];
            __builtin_memcpy(&Wf[g][kc], &tt, 16);
        }
    // step-persistent accumulators; bias rides in element 0, elements 1-3 are don't-cares
    f32x4 z4 = {0.f, 0.f, 0.f, 0.f};
    f32x4 acc[5];
    #pragma unroll
    for (int g = 0; g < 5; ++g) acc[g] = z4;

    float c_sel = enc[100 + rc];        // c of M_0 for this lane's row

    // 4-deep prefetch ring: slot u holds P row (1+u) gate biases + enc c2 row (1+u)
    float pr[4][6];
    #pragma unroll
    for (int u = 0; u < 4; ++u) {
        const float* pu4 = P + (size_t)(1 + u) * PSTRIDE + rc * 4;   // 16B aligned
        const float4 g4 = *(const float4*)pu4;
        pr[u][0] = g4.x; pr[u][1] = g4.y; pr[u][2] = g4.z; pr[u][3] = g4.w;
        pr[u][4] = P[(size_t)(1 + u) * PSTRIDE + 400 + rc];
        pr[u][5] = enc[(size_t)(1 + u) * HID + 100 + rc];
    }
    const float* pP4 = P + (size_t)5 * PSTRIDE + rc * 4;   // next prefetch = step 5
    const float* pPu = P + (size_t)5 * PSTRIDE + 400 + rc;
    const float* pE  = enc + (size_t)5 * HID + 100 + rc;
    float* pM = M + HID + 2 * r;                           // step-1 store slot (act-guarded)
    BAR();

    // main loop: 8190 iterations x 4 steps = steps 1..32760
    for (int base = 1; base <= KMAX - 9; base += 4) {
        BODY(0, true);
        BODY(1, true);
        BODY(2, true);
        BODY(3, true);
    }
    // tail: steps 32761..32766 (slots 0,1 reloaded for 32765/32766)
    BODY(0, true);
    BODY(1, true);
    BODY(2, false);
    BODY(3, false);
    BODY(0, false);
    BODY(1, false);
}

// ---------------- per-step CE losses + reduction ----------------
__global__ __launch_bounds__(256) void loss_kernel(const float* __restrict__ TM,
    const float* __restrict__ TE, const float* __restrict__ msAB, const float* __restrict__ msBC,
    const float* __restrict__ b_act, const float* __restrict__ b_lab, const float* __restrict__ b_dir,
    const int* __restrict__ ga, const int* __restrict__ gl, const int* __restrict__ gd,
    float* __restrict__ out)
{
    const int t = blockIdx.x * 256 + threadIdx.x;
    float loss = 0.f;
    if (t < N_STEPS) {
        const float *v1, *v0, *vb;
        if (t == 0)      { v1 = msAB; v0 = msAB + 24; vb = TE + 24; }
        else if (t == 1) { v1 = msAB; v0 = TE;        vb = TE + 48 + 24; }
        else if ((t & 1) == 0) {
            const int k = t >> 1;
            v1 = TM + (size_t)(k - 1) * 48;
            v0 = TE + (size_t)k * 48;
            vb = (k < N_EDUS - 1) ? (TE + (size_t)(k + 1) * 48 + 24) : (msBC + 24);
        } else {
            const int k = t >> 1;
            v1 = msAB;
            v0 = TM + (size_t)k * 48 + 24;
            vb = TE + (size_t)(k + 1) * 48 + 24;
        }
        float l[24];
        #pragma unroll
        for (int j = 0; j < 24; ++j) l[j] = v1[j] + v0[j] + vb[j];
        l[0] += b_act[0]; l[1] += b_act[1];
        #pragma unroll
        for (int j = 0; j < 19; ++j) l[2 + j] += b_lab[j];
        #pragma unroll
        for (int j = 0; j < 3; ++j) l[21 + j] += b_dir[j];
        const int ya = ga[t], yl = gl[t], yd = gd[t];
        {
            const float m = fmaxf(l[0], l[1]);
            const float sum = __expf(l[0] - m) + __expf(l[1] - m);
            loss += m + __logf(sum) - (ya == 0 ? l[0] : l[1]);
        }
        {
            float m = l[2];
            #pragma unroll
            for (int j = 1; j < 19; ++j) m = fmaxf(m, l[2 + j]);
            float sum = 0.f, ly = 0.f;
            #pragma unroll
            for (int j = 0; j < 19; ++j) {
                sum += __expf(l[2 + j] - m);
                if (j == yl) ly = l[2 + j];
            }
            loss += m + __logf(sum) - ly;
        }
        {
            const float m = fmaxf(fmaxf(l[21], l[22]), l[23]);
            const float sum = __expf(l[21] - m) + __expf(l[22] - m) + __expf(l[23] - m);
            const float ly = (yd == 0) ? l[21] : (yd == 1 ? l[22] : l[23]);
            loss += m + __logf(sum) - ly;
        }
    }
    #pragma unroll
    for (int off = 32; off > 0; off >>= 1) loss += __shfl_down(loss, off, 64);
    __shared__ float wsum[4];
    const int lane = threadIdx.x & 63, wv = threadIdx.x >> 6;
    if (lane == 0) wsum[wv] = loss;
    __syncthreads();
    if (threadIdx.x == 0) atomicAdd(out, wsum[0] + wsum[1] + wsum[2] + wsum[3]);
}

// ---------------- launch ----------------
extern "C" void kernel_launch(void* const* d_in, const int* in_sizes, int n_in,
                              void* d_out, int out_size, void* d_ws, size_t ws_size,
                              hipStream_t stream) {
    const float* enc_cls = (const float*)d_in[0];
    const float* W_proj  = (const float*)d_in[1];
    const float* b_proj  = (const float*)d_in[2];
    const float* miss    = (const float*)d_in[3];
    const float* W_act   = (const float*)d_in[4];
    const float* b_act   = (const float*)d_in[5];
    const float* W_lab   = (const float*)d_in[6];
    const float* b_lab   = (const float*)d_in[7];
    const float* W_dir   = (const float*)d_in[8];
    const float* b_dir   = (const float*)d_in[9];
    const float* W_tree  = (const float*)d_in[10];
    const float* b_tree  = (const float*)d_in[11];
    const int*   ga      = (const int*)d_in[12];
    const int*   gl      = (const int*)d_in[13];
    const int*   gd      = (const int*)d_in[14];
    float* out = (float*)d_out;

    float* ws   = (float*)d_ws;
    float* enc  = ws;                         // 32768*200
    float* Mar  = ws + 6553600;               // 32767*200 (interleaved h,c pairs)
    float* P    = ws + 13107000;              // 32767*500 (4+1 gate layout, row 0 unused)
    float* WAB  = ws + 29490500;              // 48*200 (interleaved cols)
    float* WBC  = WAB + 9600;                 // 48*200
    float* msAB = WBC + 9600;                 // 48
    float* msBC = msAB + 48;                  // 48
    uint4* WB   = (uint4*)(msBC + 48);        // 8960 uint4 = 35840 dwords (B-frags)
    float* TM = P;                            // 32767*48 (overlays dead P)
    float* TE = P + 1572816;                  // 32768*48

    gemm_bt<<<dim3(512, 4, 1), 256, 0, stream>>>(enc_cls, 768, W_proj, 768, b_proj,
                                                 enc, 200, N_EDUS, 200, 768, 0);
    gemm_bt<<<dim3(512, 8, 1), 256, 0, stream>>>(enc + 200, 200, W_tree + 100, 200, b_tree,
                                                 P + PSTRIDE, PSTRIDE, KMAX, 500, 100, 1);
    prep_kernel<<<1, 256, 0, stream>>>(W_act, W_lab, W_dir, miss, WAB, WBC, msAB, msBC, out);
    pack_wb<<<35, 256, 0, stream>>>(W_tree, WB);
    chain_kernel<<<1, 448, 0, stream>>>(enc, WB, P, Mar);
    gemm_bt<<<dim3(512, 1, 1), 256, 0, stream>>>(Mar, 200, WAB, 200, nullptr,
                                                 TM, 48, KMAX + 1, 48, 200, 0);
    gemm_bt<<<dim3(512, 1, 1), 256, 0, stream>>>(enc, 200, WBC, 200, nullptr,
                                                 TE, 48, N_EDUS, 48, 200, 0);
    loss_kernel<<<dim3(256, 1, 1), 256, 0, stream>>>(TM, TE, msAB, msBC,
                                                     b_act, b_lab, b_dir, ga, gl, gd, out);
}